// Round 5
// baseline (1517.377 us; speedup 1.0000x reference)
//
#include <hip/hip_runtime.h>

#define BB 1024
#define TT 512
#define KK 64
#define NEGV -10000.0f

typedef _Float16 h2 __attribute__((ext_vector_type(2)));

#if defined(__has_builtin)
#if __has_builtin(__builtin_amdgcn_fdot2)
#define HAVE_FDOT2 1
#endif
#endif

static __device__ __forceinline__ float dot2_acc(h2 a, h2 b, float c) {
#ifdef HAVE_FDOT2
    return __builtin_amdgcn_fdot2(a, b, c, false);
#else
    return fmaf((float)a.x, (float)b.x, fmaf((float)a.y, (float)b.y, c));
#endif
}

static __device__ __forceinline__ h2 bc_h2(float f) {
    return __builtin_bit_cast(h2, f);
}

// ---------------------------------------------------------------------------
// crf_kernel: ONE wave per batch, F and V recurrences MERGED in one
// instruction stream (independent chains -> ILP hides each other's DS/VALU
// latency; this beat the 2-wave split which left 70% of the step exposed).
//  - forward: f16 ea broadcast + v_dot2, 2-deep pipelined wave-uniform ref
//  - viterbi: exact fp32; all 64 candidates kept in VGPRs; REGISTER-ONLY
//    argmax epilogue (group tree + cndmask select) -> no in-loop global loads
//  - feats prefetch depth 4; bp in LDS; shfl-chain backtrace
//  - gold score folded into the block prologue
// ---------------------------------------------------------------------------
__global__ __launch_bounds__(64, 1) void crf_kernel(const float* __restrict__ feats,
                                                    const int* __restrict__ tags,
                                                    const float* __restrict__ trans,
                                                    float* __restrict__ out) {
    __shared__ unsigned char bp[TT][KK];            // 32 KB backpointers
    __shared__ __align__(16) float wa_buf[KK];      // viterbi alpha broadcast
    __shared__ __align__(16) _Float16 ea_buf[KK];   // exp(alpha - ref), f16

    const int b = blockIdx.x;
    const int lane = threadIdx.x;

    // ---- gold score (one-time, lane-parallel gather) ----
    const int* tg = tags + (size_t)b * TT;
    float gold = 0.f;
#pragma unroll
    for (int i = 0; i < TT / 64; ++i) {
        int t = lane + i * 64;
        int nxt = tg[t];
        int prv = t ? tg[t - 1] : 0;
        gold += trans[nxt * KK + prv] + feats[((size_t)b * TT + t) * KK + nxt];
    }
    if (lane == 0) gold += trans[(KK - 1) * KK + tg[TT - 1]];  // STOP term
#pragma unroll
    for (int d = 1; d < 64; d <<= 1) gold += __shfl_xor(gold, d);

    // ---- per-lane transition row (lane = next state) ----
    float tr[KK];
    h2 Er_pk[KK / 2];   // exp(tr) packed f16 pairs for the forward dot2
    {
        const float4* trow = reinterpret_cast<const float4*>(trans + lane * KK);
#pragma unroll
        for (int i = 0; i < KK / 4; ++i) {
            float4 v = trow[i];
            tr[4 * i + 0] = v.x; tr[4 * i + 1] = v.y;
            tr[4 * i + 2] = v.z; tr[4 * i + 3] = v.w;
            h2 lo, hi;
            lo.x = (_Float16)__expf(v.x); lo.y = (_Float16)__expf(v.y);
            hi.x = (_Float16)__expf(v.z); hi.y = (_Float16)__expf(v.w);
            Er_pk[2 * i] = lo;
            Er_pk[2 * i + 1] = hi;
        }
    }
    const float t63 = trans[(KK - 1) * KK + lane];  // trans[STOP][lane]

    float a = (lane == 0) ? 0.f : NEGV;   // forward alpha (log domain)
    float w = a;                          // viterbi alpha
    wa_buf[lane] = w;
    // pipelined wave-uniform normalizer: refUse(t) = shfl(a_{t-2}, 8) + 5
    float refUse = 0.f, refMid = 6.f, refNew = 12.f;

    // feats prefetch ring, depth 4
    const float* fbp = feats + (size_t)b * TT * KK + lane;
    float f0 = fbp[0 * KK];
    float f1 = fbp[1 * KK];
    float f2 = fbp[2 * KK];
    float f3 = fbp[3 * KK];
    const float* fp = fbp + 4 * KK;

    for (int t = 0; t < TT; ++t) {
        const float f_cur = f0;
        f0 = f1; f1 = f2; f2 = f3;
        f3 = *fp;                       // row min(t+4, TT-1)
        if (t + 5 < TT) fp += KK;

        // ======== forward: publish normalized exp(alpha) ========
        float x = fminf(a - refUse, 11.0f);     // e^11 < f16 max
        ea_buf[lane] = (_Float16)__expf(x);
        // single-wave block: in-order DS pipe, no barrier needed

        // ======== viterbi: candidates + group maxima (all in VGPRs) ========
        float c[KK];
        float gm[8];
        const float4* wb = reinterpret_cast<const float4*>(wa_buf);
#pragma unroll
        for (int g = 0; g < 8; ++g) {
            float4 wA = wb[2 * g];
            float4 wB = wb[2 * g + 1];
            float c0 = wA.x + tr[8 * g + 0];
            float c1 = wA.y + tr[8 * g + 1];
            float c2 = wA.z + tr[8 * g + 2];
            float c3 = wA.w + tr[8 * g + 3];
            float c4 = wB.x + tr[8 * g + 4];
            float c5 = wB.y + tr[8 * g + 5];
            float c6 = wB.z + tr[8 * g + 6];
            float c7 = wB.w + tr[8 * g + 7];
            c[8 * g + 0] = c0; c[8 * g + 1] = c1;
            c[8 * g + 2] = c2; c[8 * g + 3] = c3;
            c[8 * g + 4] = c4; c[8 * g + 5] = c5;
            c[8 * g + 6] = c6; c[8 * g + 7] = c7;
            gm[g] = fmaxf(fmaxf(fmaxf(c0, c1), fmaxf(c2, c3)),
                          fmaxf(fmaxf(c4, c5), fmaxf(c6, c7)));
        }

        // ======== forward: dot-products over the broadcast ========
        const float4* eb = reinterpret_cast<const float4*>(ea_buf);
        float s0 = 0.f, s1 = 0.f, s2 = 0.f, s3 = 0.f;
        float s4 = 0.f, s5 = 0.f, s6 = 0.f, s7 = 0.f;
#pragma unroll
        for (int q = 0; q < 8; ++q) {
            float4 e4 = eb[q];
            float acc = 0.f;
            acc = dot2_acc(bc_h2(e4.x), Er_pk[4 * q + 0], acc);
            acc = dot2_acc(bc_h2(e4.y), Er_pk[4 * q + 1], acc);
            acc = dot2_acc(bc_h2(e4.z), Er_pk[4 * q + 2], acc);
            acc = dot2_acc(bc_h2(e4.w), Er_pk[4 * q + 3], acc);
            switch (q) {
                case 0: s0 = acc; break; case 1: s1 = acc; break;
                case 2: s2 = acc; break; case 3: s3 = acc; break;
                case 4: s4 = acc; break; case 5: s5 = acc; break;
                case 6: s6 = acc; break; case 7: s7 = acc; break;
            }
        }
        float s = ((s0 + s1) + (s2 + s3)) + ((s4 + s5) + (s6 + s7));
        float a_new = __logf(s) + refUse + f_cur;
        refUse = refMid;
        refMid = refNew;
        refNew = __shfl(a_new, 8) + 5.0f;   // consumed 2 iterations later
        a = a_new;

        // ======== viterbi: max, publish, register-only argmax ========
        float m = fmaxf(fmaxf(fmaxf(gm[0], gm[1]), fmaxf(gm[2], gm[3])),
                        fmaxf(fmaxf(gm[4], gm[5]), fmaxf(gm[6], gm[7])));
        float w_new = m + f_cur;
        wa_buf[lane] = w_new;   // after all wb reads (same buffer: not reordered)
        w = w_new;

        int g = 0;
#pragma unroll
        for (int j = 7; j >= 0; --j)        // descending: smallest group wins
            if (gm[j] == m) g = j;
        const bool bit0 = (g & 1), bit1 = (g & 2), bit2 = (g & 4);
        const int base = g << 3;
        int bpv = base;
#pragma unroll
        for (int j = 7; j >= 0; --j) {      // descending: smallest index wins
            float x0 = bit2 ? c[32 + j] : c[0 + j];
            float x1 = bit2 ? c[40 + j] : c[8 + j];
            float x2 = bit2 ? c[48 + j] : c[16 + j];
            float x3 = bit2 ? c[56 + j] : c[24 + j];
            float y0 = bit1 ? x2 : x0;
            float y1 = bit1 ? x3 : x1;
            float cj = bit0 ? y1 : y0;
            if (cj == m) bpv = base + j;
        }
        bp[t][lane] = (unsigned char)bpv;
    }

    // ---- forward score: exact logsumexp(alpha_T + trans[STOP][:]) ----
    float v = a + t63;
    float mm = v;
#pragma unroll
    for (int d = 32; d; d >>= 1) mm = fmaxf(mm, __shfl_xor(mm, d));
    float es = __expf(v - mm);
#pragma unroll
    for (int d = 32; d; d >>= 1) es += __shfl_xor(es, d);
    float fscore = mm + __logf(es);

    // ---- viterbi terminal: max + first-index argmax (exact) ----
    float tv = w + t63;
    float bvv = tv;
    int bidx = lane;
#pragma unroll
    for (int d = 1; d < 64; d <<= 1) {
        float ov = __shfl_xor(bvv, d);
        int oi = __shfl_xor(bidx, d);
        bool take = (ov > bvv) || (ov == bvv && oi < bidx);
        bvv = take ? ov : bvv;
        bidx = take ? oi : bidx;
    }

    if (lane == 0) {
        out[b] = fscore - gold;
        out[BB + b] = bvv;
    }

    // ---- backtrace: bulk LDS row loads + dynamic-shfl chain ----
    float* outp = out + 2 * BB + (size_t)b * TT;
    int cur = bidx;                 // wave-uniform
    float my = 0.f;                 // latched path values (lane = t & 63)
    for (int tb = TT - 16; tb >= 0; tb -= 16) {
        int r[16];
#pragma unroll
        for (int j = 0; j < 16; ++j) r[j] = bp[tb + j][lane];
#pragma unroll
        for (int j = 15; j >= 0; --j) {
            my = (lane == ((tb + j) & 63)) ? (float)cur : my;
            cur = __shfl(r[j], cur);
        }
        if ((tb & 63) == 0) outp[tb + lane] = my;   // coalesced 64-wide store
    }
}

extern "C" void kernel_launch(void* const* d_in, const int* in_sizes, int n_in,
                              void* d_out, int out_size, void* d_ws, size_t ws_size,
                              hipStream_t stream) {
    const float* feats = (const float*)d_in[0];
    const int* tags = (const int*)d_in[1];
    const float* trans = (const float*)d_in[2];
    float* out = (float*)d_out;

    crf_kernel<<<BB, 64, 0, stream>>>(feats, tags, trans, out);
}

// Round 6
// 350.842 us; speedup vs baseline: 4.3250x; 4.3250x over previous
//
#include <hip/hip_runtime.h>

#define BB 1024
#define TT 512
#define KK 64
#define NEGV -10000.0f

typedef _Float16 h2 __attribute__((ext_vector_type(2)));

#if defined(__has_builtin)
#if __has_builtin(__builtin_amdgcn_fdot2)
#define HAVE_FDOT2 1
#endif
#endif

static __device__ __forceinline__ float dot2_acc(h2 a, h2 b, float c) {
#ifdef HAVE_FDOT2
    return __builtin_amdgcn_fdot2(a, b, c, false);
#else
    return fmaf((float)a.x, (float)b.x, fmaf((float)a.y, (float)b.y, c));
#endif
}

static __device__ __forceinline__ h2 bc_h2(float f) {
    return __builtin_bit_cast(h2, f);
}

// ---------------------------------------------------------------------------
// crf_kernel: ONE wave per batch, F and V merged in one instruction stream
// (independent chains hide each other's DS/VALU latency). R5's register-only
// epilogue spilled (c[64] blew the VGPR budget -> 2 GB scratch traffic); this
// version uses R4's DEFERRED epilogue instead: the argmax operand re-reads
// (wa_buf LDS + trans global, both bitwise-identical sources) are issued at
// the end of step t and consumed at the top of step t+1 -> zero live c[]
// array, zero exposed load latency.
//  - forward: f16 ea broadcast + v_dot2, 2-deep pipelined wave-uniform ref
//  - viterbi: exact fp32 adds/maxes, first-index tie-breaks (absmax 0 in R4)
//  - feats prefetch depth 4; bp in LDS; shfl-chain backtrace; gold inline
// ---------------------------------------------------------------------------
__global__ __launch_bounds__(64, 1) void crf_kernel(const float* __restrict__ feats,
                                                    const int* __restrict__ tags,
                                                    const float* __restrict__ trans,
                                                    float* __restrict__ out) {
    __shared__ unsigned char bp[TT][KK];            // 32 KB backpointers
    __shared__ __align__(16) float wa_buf[KK];      // viterbi alpha broadcast
    __shared__ __align__(16) _Float16 ea_buf[KK];   // exp(alpha - ref), f16

    const int b = blockIdx.x;
    const int lane = threadIdx.x;

    // ---- gold score (one-time, lane-parallel gather) ----
    const int* tg = tags + (size_t)b * TT;
    float gold = 0.f;
#pragma unroll
    for (int i = 0; i < TT / 64; ++i) {
        int t = lane + i * 64;
        int nxt = tg[t];
        int prv = t ? tg[t - 1] : 0;
        gold += trans[nxt * KK + prv] + feats[((size_t)b * TT + t) * KK + nxt];
    }
    if (lane == 0) gold += trans[(KK - 1) * KK + tg[TT - 1]];  // STOP term
#pragma unroll
    for (int d = 1; d < 64; d <<= 1) gold += __shfl_xor(gold, d);

    // ---- per-lane transition row (lane = next state) ----
    float tr[KK];
    h2 Er_pk[KK / 2];   // exp(tr) packed f16 pairs for the forward dot2
    {
        const float4* trow = reinterpret_cast<const float4*>(trans + lane * KK);
#pragma unroll
        for (int i = 0; i < KK / 4; ++i) {
            float4 v = trow[i];
            tr[4 * i + 0] = v.x; tr[4 * i + 1] = v.y;
            tr[4 * i + 2] = v.z; tr[4 * i + 3] = v.w;
            h2 lo, hi;
            lo.x = (_Float16)__expf(v.x); lo.y = (_Float16)__expf(v.y);
            hi.x = (_Float16)__expf(v.z); hi.y = (_Float16)__expf(v.w);
            Er_pk[2 * i] = lo;
            Er_pk[2 * i + 1] = hi;
        }
    }
    const float t63 = trans[(KK - 1) * KK + lane];  // trans[STOP][lane]

    float a = (lane == 0) ? 0.f : NEGV;   // forward alpha (log domain)
    float w = a;                          // viterbi alpha
    wa_buf[lane] = w;
    // pipelined wave-uniform normalizer: refUse(t) = shfl(a_{t-2}, 8) + 5
    float refUse = 0.f, refMid = 6.f, refNew = 12.f;

    // feats prefetch ring, depth 4
    const float* fbp = feats + (size_t)b * TT * KK + lane;
    float f0 = fbp[0 * KK];
    float f1 = fbp[1 * KK];
    float f2 = fbp[2 * KK];
    float f3 = fbp[3 * KK];
    const float* fp = fbp + 4 * KK;

    // pending (deferred) epilogue state for step t-1
    float4 p_wa0 = {}, p_wa1 = {}, p_tg0 = {}, p_tg1 = {};
    float p_m = 0.f;
    int p_base = 0;

    for (int t = 0; t < TT; ++t) {
        // ---- finish step t-1: argmax compare + bp store (operands have had a
        //      full iteration of latency cover) ----
        if (t) {
            int bpv = p_base;
            float vv;
            vv = p_wa1.w + p_tg1.w; if (vv == p_m) bpv = p_base + 7;
            vv = p_wa1.z + p_tg1.z; if (vv == p_m) bpv = p_base + 6;
            vv = p_wa1.y + p_tg1.y; if (vv == p_m) bpv = p_base + 5;
            vv = p_wa1.x + p_tg1.x; if (vv == p_m) bpv = p_base + 4;
            vv = p_wa0.w + p_tg0.w; if (vv == p_m) bpv = p_base + 3;
            vv = p_wa0.z + p_tg0.z; if (vv == p_m) bpv = p_base + 2;
            vv = p_wa0.y + p_tg0.y; if (vv == p_m) bpv = p_base + 1;
            vv = p_wa0.x + p_tg0.x; if (vv == p_m) bpv = p_base + 0;
            bp[t - 1][lane] = (unsigned char)bpv;
        }

        const float f_cur = f0;
        f0 = f1; f1 = f2; f2 = f3;
        f3 = *fp;                       // row min(t+4, TT-1)
        if (t + 5 < TT) fp += KK;

        // ======== forward: publish normalized exp(alpha) ========
        float x = fminf(a - refUse, 11.0f);     // e^11 < f16 max
        ea_buf[lane] = (_Float16)__expf(x);
        // single-wave block: in-order DS pipe, no barrier needed

        // ======== viterbi: candidates + group maxima (no c[] kept!) ========
        float gm[8];
        const float4* wb = reinterpret_cast<const float4*>(wa_buf);
#pragma unroll
        for (int g = 0; g < 8; ++g) {
            float4 wA = wb[2 * g];
            float4 wB = wb[2 * g + 1];
            float c0 = wA.x + tr[8 * g + 0];
            float c1 = wA.y + tr[8 * g + 1];
            float c2 = wA.z + tr[8 * g + 2];
            float c3 = wA.w + tr[8 * g + 3];
            float c4 = wB.x + tr[8 * g + 4];
            float c5 = wB.y + tr[8 * g + 5];
            float c6 = wB.z + tr[8 * g + 6];
            float c7 = wB.w + tr[8 * g + 7];
            gm[g] = fmaxf(fmaxf(fmaxf(c0, c1), fmaxf(c2, c3)),
                          fmaxf(fmaxf(c4, c5), fmaxf(c6, c7)));
        }

        // ======== forward: dot-products over the broadcast ========
        const float4* eb = reinterpret_cast<const float4*>(ea_buf);
        float s0 = 0.f, s1 = 0.f, s2 = 0.f, s3 = 0.f;
        float s4 = 0.f, s5 = 0.f, s6 = 0.f, s7 = 0.f;
#pragma unroll
        for (int q = 0; q < 8; ++q) {
            float4 e4 = eb[q];
            float acc = 0.f;
            acc = dot2_acc(bc_h2(e4.x), Er_pk[4 * q + 0], acc);
            acc = dot2_acc(bc_h2(e4.y), Er_pk[4 * q + 1], acc);
            acc = dot2_acc(bc_h2(e4.z), Er_pk[4 * q + 2], acc);
            acc = dot2_acc(bc_h2(e4.w), Er_pk[4 * q + 3], acc);
            switch (q) {   // 8 independent chains
                case 0: s0 = acc; break; case 1: s1 = acc; break;
                case 2: s2 = acc; break; case 3: s3 = acc; break;
                case 4: s4 = acc; break; case 5: s5 = acc; break;
                case 6: s6 = acc; break; case 7: s7 = acc; break;
            }
        }
        float s = ((s0 + s1) + (s2 + s3)) + ((s4 + s5) + (s6 + s7));
        float a_new = __logf(s) + refUse + f_cur;
        refUse = refMid;
        refMid = refNew;
        refNew = __shfl(a_new, 8) + 5.0f;   // consumed 2 iterations later
        a = a_new;

        // ======== viterbi: max, group select, issue deferred loads ========
        float m = fmaxf(fmaxf(fmaxf(gm[0], gm[1]), fmaxf(gm[2], gm[3])),
                        fmaxf(fmaxf(gm[4], gm[5]), fmaxf(gm[6], gm[7])));
        int g = 0;
#pragma unroll
        for (int j = 7; j >= 0; --j)   // descending: smallest matching group
            if (gm[j] == m) g = j;
        const int base = g * 8;

        // re-reads consumed NEXT iteration; wa reads BEFORE the write (old vals)
        const float4* wam = reinterpret_cast<const float4*>(wa_buf + base);
        p_wa0 = wam[0];
        p_wa1 = wam[1];
        wa_buf[lane] = m + f_cur;           // in-order DS pipe: reads saw old
        const float4* trg = reinterpret_cast<const float4*>(trans + lane * KK + base);
        p_tg0 = trg[0];
        p_tg1 = trg[1];                     // L1/L2-resident, full-step cover
        p_m = m;
        p_base = base;
        w = m + f_cur;
    }
    // finish last step's bp
    {
        int bpv = p_base;
        float vv;
        vv = p_wa1.w + p_tg1.w; if (vv == p_m) bpv = p_base + 7;
        vv = p_wa1.z + p_tg1.z; if (vv == p_m) bpv = p_base + 6;
        vv = p_wa1.y + p_tg1.y; if (vv == p_m) bpv = p_base + 5;
        vv = p_wa1.x + p_tg1.x; if (vv == p_m) bpv = p_base + 4;
        vv = p_wa0.w + p_tg0.w; if (vv == p_m) bpv = p_base + 3;
        vv = p_wa0.z + p_tg0.z; if (vv == p_m) bpv = p_base + 2;
        vv = p_wa0.y + p_tg0.y; if (vv == p_m) bpv = p_base + 1;
        vv = p_wa0.x + p_tg0.x; if (vv == p_m) bpv = p_base + 0;
        bp[TT - 1][lane] = (unsigned char)bpv;
    }

    // ---- forward score: exact logsumexp(alpha_T + trans[STOP][:]) ----
    float v = a + t63;
    float mm = v;
#pragma unroll
    for (int d = 32; d; d >>= 1) mm = fmaxf(mm, __shfl_xor(mm, d));
    float es = __expf(v - mm);
#pragma unroll
    for (int d = 32; d; d >>= 1) es += __shfl_xor(es, d);
    float fscore = mm + __logf(es);

    // ---- viterbi terminal: max + first-index argmax (exact) ----
    float tv = w + t63;
    float bvv = tv;
    int bidx = lane;
#pragma unroll
    for (int d = 1; d < 64; d <<= 1) {
        float ov = __shfl_xor(bvv, d);
        int oi = __shfl_xor(bidx, d);
        bool take = (ov > bvv) || (ov == bvv && oi < bidx);
        bvv = take ? ov : bvv;
        bidx = take ? oi : bidx;
    }

    if (lane == 0) {
        out[b] = fscore - gold;
        out[BB + b] = bvv;
    }

    // ---- backtrace: bulk LDS row loads + dynamic-shfl chain ----
    float* outp = out + 2 * BB + (size_t)b * TT;
    int cur = bidx;                 // wave-uniform
    float my = 0.f;                 // latched path values (lane = t & 63)
    for (int tb = TT - 16; tb >= 0; tb -= 16) {
        int r[16];
#pragma unroll
        for (int j = 0; j < 16; ++j) r[j] = bp[tb + j][lane];
#pragma unroll
        for (int j = 15; j >= 0; --j) {
            my = (lane == ((tb + j) & 63)) ? (float)cur : my;
            cur = __shfl(r[j], cur);
        }
        if ((tb & 63) == 0) outp[tb + lane] = my;   // coalesced 64-wide store
    }
}

extern "C" void kernel_launch(void* const* d_in, const int* in_sizes, int n_in,
                              void* d_out, int out_size, void* d_ws, size_t ws_size,
                              hipStream_t stream) {
    const float* feats = (const float*)d_in[0];
    const int* tags = (const int*)d_in[1];
    const float* trans = (const float*)d_in[2];
    float* out = (float*)d_out;

    crf_kernel<<<BB, 64, 0, stream>>>(feats, tags, trans, out);
}